// Round 15
// baseline (136.532 us; speedup 1.0000x reference)
//
#include <hip/hip_runtime.h>
#include <math.h>

#define B_   8
#define CIN  256
#define COUT 256
#define H_   64
#define W_   64
#define HO   62
#define WO   62
#define SDIM 512

// convout padded: [b][co][62][64] bf16
#define CSTRIDE 64

typedef __attribute__((ext_vector_type(8))) short bf16x8;
typedef __attribute__((ext_vector_type(4))) float f32x4;

__device__ __forceinline__ unsigned short f2bf(float f) {
    unsigned int u = __float_as_uint(f);
    u += 0x7fffu + ((u >> 16) & 1u);
    return (unsigned short)(u >> 16);
}
__device__ __forceinline__ float bf2f(unsigned short h) {
    return __uint_as_float(((unsigned int)h) << 16);
}

// ws layout (floats):
// s:       [0, 2048)
// dm:      [2048, 4096)
// wsq:     [4096, 69632)
// wh:      [69632, 364544)     (9*256*256 ushort, hi only)
// zpage:   [364544, 365056)    (512 floats, zeroed by mod_kernel each launch)
// xh:      [659456, 4853760)   (8*64*64*256 ushort)
// convout: [9048064, 13111296) (8*256*62*64 ushort)

__global__ void mod_kernel(const float* __restrict__ style, const float* __restrict__ mod_w,
                           const float* __restrict__ mod_b, float* __restrict__ s_out,
                           float* __restrict__ zpage) {
    if (blockIdx.x == 0) {
        zpage[threadIdx.x] = 0.f;
        zpage[threadIdx.x + 256] = 0.f;
    }
    int wid = blockIdx.x * 4 + (threadIdx.x >> 6);
    int lane = threadIdx.x & 63;
    int b = wid >> 8, ci = wid & 255;
    float acc = 0.f;
    const float* st = style + b * SDIM;
    const float* mw = mod_w + ci * SDIM;
    for (int i = 0; i < SDIM; i += 64) acc += st[i + lane] * mw[i + lane];
    for (int m = 32; m >= 1; m >>= 1) acc += __shfl_xor(acc, m, 64);
    if (lane == 0) s_out[wid] = acc * 0.04419417382415922f + mod_b[ci]; // 1/sqrt(512)
}

__global__ void wsplit_kernel(const float* __restrict__ cw, float* __restrict__ wsq,
                              unsigned short* __restrict__ wh) {
    int idx = blockIdx.x * blockDim.x + threadIdx.x; // co*256+ci
    int co = idx >> 8, ci = idx & 255;
    const float* p = cw + (size_t)idx * 9;
    float ss = 0.f;
#pragma unroll
    for (int k = 0; k < 9; ++k) {
        float v = p[k];
        ss += v * v;
        wh[(k * COUT + co) * CIN + ci] = f2bf(v);
    }
    wsq[idx] = ss;
}

__global__ void demod_kernel(const float* __restrict__ s_in, const float* __restrict__ wsq,
                             float* __restrict__ dm) {
    int wid = blockIdx.x * 4 + (threadIdx.x >> 6);
    int lane = threadIdx.x & 63;
    int b = wid >> 8, co = wid & 255;
    float acc = 0.f;
    for (int i = 0; i < CIN; i += 64) {
        float sv = s_in[b * CIN + i + lane];
        acc += sv * sv * wsq[co * CIN + i + lane];
    }
    for (int m = 32; m >= 1; m >>= 1) acc += __shfl_xor(acc, m, 64);
    if (lane == 0) {
        const float scale = 0.020833333333333332f; // 1/48 = 1/sqrt(2304)
        float demod = rsqrtf(scale * scale * acc + 1e-8f);
        dm[wid] = demod * scale / (1.f + 1e-8f);
    }
}

// Transpose+scale: x[b][ci][y][x] f32 -> xh[b][y][x][ci] bf16.
__global__ __launch_bounds__(256) void xsplit_kernel(
        const float* __restrict__ x, const float* __restrict__ s_in,
        unsigned short* __restrict__ xh) {
    __shared__ float tile[128 * 65];
    __shared__ float s_loc[256];
    int b = blockIdx.x >> 6;
    int y = blockIdx.x & 63;
    int tid = threadIdx.x;
    s_loc[tid] = s_in[(b << 8) + tid];
    __syncthreads();
    for (int half = 0; half < 2; ++half) {
        int cb = half << 7;
        for (int f = tid; f < 2048; f += 256) {
            int ci = f >> 4, x4 = (f & 15) << 2;
            float4 v = *(const float4*)(x + ((((size_t)b << 8) + cb + ci) << 12) + (y << 6) + x4);
            float sv = s_loc[cb + ci];
            float* t = tile + ci * 65 + x4;
            t[0] = v.x * sv; t[1] = v.y * sv; t[2] = v.z * sv; t[3] = v.w * sv;
        }
        __syncthreads();
        for (int g = tid; g < 1024; g += 256) {
            int c = g & 15, xx = g >> 4;   // c: 8-ci chunk, xx: x position
            unsigned int hw[4];
#pragma unroll
            for (int q = 0; q < 4; ++q) {
                float v0 = tile[(c * 8 + 2 * q) * 65 + xx];
                float v1 = tile[(c * 8 + 2 * q + 1) * 65 + xx];
                hw[q] = (unsigned int)f2bf(v0) | ((unsigned int)f2bf(v1) << 16);
            }
            int o = ((((b << 6) + y) << 6) + xx) * 256 + cb + (c << 3);
            *(uint4*)(xh + o) = make_uint4(hw[0], hw[1], hw[2], hw[3]);
        }
        __syncthreads();
    }
}

// DMA staging helpers (global_load_lds, width 16): linear LDS dest, source
// carries the XOR bank-swizzle (pre-swizzled-source pattern).
__device__ __forceinline__ void stage_b(const unsigned short* wh, const int* bsrc,
                                        short* dst, int tid, int kyci) {
#pragma unroll
    for (int j = 0; j < 6; ++j)
        __builtin_amdgcn_global_load_lds(
            (const __attribute__((address_space(1))) unsigned int*)(wh + bsrc[j] + kyci),
            (__attribute__((address_space(3))) unsigned int*)(dst + ((tid + (j << 8)) << 3)),
            16, 0, 0);
}
__device__ __forceinline__ void stage_a(const unsigned short* a0, const unsigned short* a1,
                                        const unsigned short* a2, short* dst, int tid, int ci0) {
    __builtin_amdgcn_global_load_lds(
        (const __attribute__((address_space(1))) unsigned int*)(a0 + ci0),
        (__attribute__((address_space(3))) unsigned int*)(dst + (tid << 3)), 16, 0, 0);
    __builtin_amdgcn_global_load_lds(
        (const __attribute__((address_space(1))) unsigned int*)(a1 + ci0),
        (__attribute__((address_space(3))) unsigned int*)(dst + ((tid + 256) << 3)), 16, 0, 0);
    __builtin_amdgcn_global_load_lds(
        (const __attribute__((address_space(1))) unsigned int*)(a2 + ci0),
        (__attribute__((address_space(3))) unsigned int*)(dst + ((tid + 512) << 3)), 16, 0, 0);
}

// compute one ky-phase (static KY): 3 kx * 4 nt * 4 yr MFMAs (hi-only)
template<int KY>
__device__ __forceinline__ void conv_compute(const short* Ah, const short* Bb,
        f32x4 (&acc)[4][4], int lrow, int lch, int wy, int wc) {
#pragma unroll
    for (int kx = 0; kx < 3; ++kx) {
        int colL = lrow + kx;
        int asw = (lch ^ ((colL >> 1) & 3)) << 3;
        bf16x8 ahf[4];
#pragma unroll
        for (int yr = 0; yr < 4; ++yr) {
            int rr = wy * 4 + yr + KY;
            ahf[yr] = *(const bf16x8*)(Ah + (rr * 18 + colL) * 32 + asw);
        }
#pragma unroll
        for (int nt = 0; nt < 4; ++nt) {
            int col = wc * 64 + nt * 16 + lrow;
            int boff = (kx << 12) + (col << 5) + ((lch ^ ((col >> 1) & 3)) << 3);
            bf16x8 bhf = *(const bf16x8*)(Bb + boff);
#pragma unroll
            for (int yr = 0; yr < 4; ++yr)
                acc[yr][nt] = __builtin_amdgcn_mfma_f32_16x16x32_bf16(ahf[yr], bhf, acc[yr][nt], 0, 0, 0);
        }
    }
}

// Implicit-GEMM modulated conv, single-pass bf16 MFMA (ah*bh), async
// double-buffered staging via global_load_lds (no VGPR round-trip).
// LDS: A0/A1 768 slots, B0/B1 1536 slots, 16B each = 73728 B -> 2 blocks/CU.
// NOTE: no pointer-arrays into LDS (addrspacecast static-init bug) — ternary
// selects on the ping-pong bit instead.
__global__ __launch_bounds__(256) void conv_mfma(
        const unsigned short* __restrict__ xh,
        const unsigned short* __restrict__ wh,
        const unsigned short* __restrict__ zpage,
        const float* __restrict__ dm,
        const float* __restrict__ bias, unsigned short* __restrict__ convout) {
    extern __shared__ short lds[];

    int tid = threadIdx.x;
    int b = blockIdx.z;
    int co0 = blockIdx.y << 7;
    int sx = blockIdx.x & 3, sy = blockIdx.x >> 2;
    int x0 = sx << 4, y0 = sy << 3;
    int wid = tid >> 6, lane = tid & 63;
    int wy = wid >> 1, wc = wid & 1;
    int lrow = lane & 15, lch = lane >> 4;

    // B source offsets (ushort idx into wh). Slot u = tid+j*256 holds chunk
    // (u&3)^sw(co) of (kx,co), so reads at slot (kx*128+co)*4 + (lch^sw) get lch.
    int bsrc[6];
#pragma unroll
    for (int j = 0; j < 6; ++j) {
        int u = tid + (j << 8);
        int chunk = u & 3;
        int co = (u >> 2) & 127;
        int kx = u >> 9;
        int cs = chunk ^ ((co >> 1) & 3);
        bsrc[j] = (kx << 16) + ((co0 + co) << 8) + (cs << 3);
    }
    // A source pointers. Slot e = tid+k*256 (<720 real, rest pad) holds chunk
    // (e&3)^sw(col) of (row,col); OOB/pad lanes read the zero page.
    const unsigned short* ap0;
    const unsigned short* ap1;
    const unsigned short* ap2;
#pragma unroll
    for (int k = 0; k < 3; ++k) {
        int u = tid + (k << 8);
        int t2 = u >> 2;
        int col = t2 % 18, row = t2 / 18;
        int yy = y0 + row, xx = x0 + col;
        bool ok = (u < 720) && (yy < 64) && (xx < 64);
        int cs = (u & 3) ^ ((col >> 1) & 3);
        const unsigned short* p = ok ? xh + ((((b << 6) + yy) << 6) + xx) * 256 + (cs << 3) : zpage;
        if (k == 0) ap0 = p; else if (k == 1) ap1 = p; else ap2 = p;
    }

    f32x4 acc[4][4];
#pragma unroll
    for (int i = 0; i < 4; ++i)
#pragma unroll
        for (int j = 0; j < 4; ++j) acc[i][j] = (f32x4){0.f, 0.f, 0.f, 0.f};

    // prologue: stage ks=0 ky=0
    stage_a(ap0, ap1, ap2, lds, tid, 0);
    stage_b(wh, bsrc, lds + 12288, tid, 0);
    __syncthreads();

#pragma unroll 1
    for (int ks = 0; ks < 8; ++ks) {
        int ci0 = ks << 5;
        int ci0n = (ks + 1) << 5;   // ks=7: harmless garbage prefetch, never read
        int pb = ks & 1;
        short* Acur = lds + (pb ? 6144 : 0);
        short* Anxt = lds + (pb ? 0 : 6144);
        short* Bcur = lds + (pb ? 24576 : 12288);
        short* Balt = lds + (pb ? 12288 : 24576);
        // phase ky=0: stage ky=1 into Balt
        stage_b(wh, bsrc, Balt, tid, 196608 + ci0);
        conv_compute<0>(Acur, Bcur, acc, lrow, lch, wy, wc);
        __syncthreads();
        // phase ky=1: stage ky=2 into Bcur
        stage_b(wh, bsrc, Bcur, tid, 2 * 196608 + ci0);
        conv_compute<1>(Acur, Balt, acc, lrow, lch, wy, wc);
        __syncthreads();
        // phase ky=2: stage next-ks ky=0 into Balt, next A into Anxt
        stage_b(wh, bsrc, Balt, tid, ci0n);
        stage_a(ap0, ap1, ap2, Anxt, tid, ci0n);
        conv_compute<2>(Acur, Bcur, acc, lrow, lch, wy, wc);
        __syncthreads();
    }

    // epilogue: D row = x-pos = 4*lch + j, D col = co = 16*nt + lrow
    int xs4 = x0 + (lch << 2);
#pragma unroll
    for (int nt = 0; nt < 4; ++nt) {
        int co = co0 + wc * 64 + nt * 16 + lrow;
        float dmv = dm[(b << 8) + co];
        float bv = bias[co];
#pragma unroll
        for (int yr = 0; yr < 4; ++yr) {
            int y = y0 + wy * 4 + yr;
            if (y < HO) {
                ushort4 o;
                o.x = f2bf(acc[yr][nt][0] * dmv + bv);
                o.y = f2bf(acc[yr][nt][1] * dmv + bv);
                o.z = f2bf(acc[yr][nt][2] * dmv + bv);
                o.w = f2bf(acc[yr][nt][3] * dmv + bv);
                *(ushort4*)(convout + ((size_t)((b << 8) + co) * HO + y) * CSTRIDE + xs4) = o;
            }
        }
    }
}

// Fused upfirdn chain per (b,c) plane. 62x62 bf16 in -> 64x64 f32 out.
// (unchanged from round 7; see aliasing-safety comment there)
__global__ __launch_bounds__(256) void filter_kernel(
        const unsigned short* __restrict__ convout, const float* __restrict__ upf,
        const float* __restrict__ dnf, float* __restrict__ out) {
    __shared__ __align__(16) float lds0[13704];
    __shared__ __align__(16) float trow2[4][2][144];
    __shared__ float uf[12], df[12];
    float* cin  = lds0;
    float* bufA = lds0 + 4464;
    float* bufB = lds0;
    int tid = threadIdx.x;
    int p = blockIdx.x;
    const unsigned short* src = convout + (size_t)p * (HO * CSTRIDE);
    float* dst = out + (size_t)p * (64 * 64);
    if (tid < 12) { uf[tid] = upf[tid] * 2.f; df[tid] = dnf[tid]; }
    for (int idx = tid; idx < 62 * 16; idx += 256) {
        int y = idx >> 4, q = idx & 15;
        ushort4 v = *(const ushort4*)(src + y * CSTRIDE + q * 4);
        if (q < 15) {
            float4 f = make_float4(bf2f(v.x), bf2f(v.y), bf2f(v.z), bf2f(v.w));
            *(float4*)(cin + y * 72 + 4 + q * 4) = f;
        } else {
            *(float2*)(cin + y * 72 + 64) = make_float2(bf2f(v.x), bf2f(v.y));
        }
    }
    for (int idx = tid; idx < 62 * 8; idx += 256) {
        int y = idx >> 3, q = idx & 7;
        cin[y * 72 + (q < 4 ? q : 62 + q)] = 0.f;
    }
    for (int idx = tid; idx < 1056; idx += 256) {
        int r = idx / 132, cc = idx - r * 132;
        bufA[(r < 4 ? r : 62 + r) * 132 + cc] = 0.f;
    }
    __syncthreads();
    for (int task = tid; task < 62 * 16; task += 256) {
        int y = task >> 4, g = task & 15;
        const float* crow = cin + y * 72 + 4 * g;
        float xv[10];
#pragma unroll
        for (int t = 0; t < 10; ++t) xv[t] = crow[t];
        float* arow = bufA + (y + 4) * 132 + 8 * g;
#pragma unroll
        for (int dd = 0; dd < 4; ++dd) {
            float oe = 0.f, oo = 0.f;
#pragma unroll
            for (int v = 0; v < 6; ++v) {
                oe += uf[2 * v + 1] * xv[dd + 5 - v];
                oo += uf[2 * v] * xv[dd + 6 - v];
            }
            *(float2*)(arow + 2 * dd) = make_float2(oe, oo);
        }
    }
    __syncthreads();
    for (int idx = tid; idx < 325; idx += 256) bufB[idx] = 0.f;

    int wid = tid >> 6, lane = tid & 63;
    float* tr0 = &trow2[wid][0][0];
    float* tr1 = &trow2[wid][1][0];
    if (lane < 5) { tr0[lane] = 0.f; tr1[lane] = 0.f; }
    if (lane < 7) { tr0[133 + lane] = 0.f; tr1[133 + lane] = 0.f; }
    const float SQ2 = 1.4142135623730951f;
    float w0[7], w1[7];
#pragma unroll
    for (int d = 0; d < 7; ++d) {
        w0[d] = bufA[(wid + d) * 132 + lane];
        w1[d] = bufA[(wid + d) * 132 + lane + 64];
    }
    for (int it = 0; it < 16; ++it) {
        int n = 4 * it + wid;
        {
            float te0 = 0.f, to0 = 0.f, te1 = 0.f, to1 = 0.f;
#pragma unroll
            for (int d = 0; d < 6; ++d) { te0 += uf[11 - 2 * d] * w0[d]; te1 += uf[11 - 2 * d] * w1[d]; }
#pragma unroll
            for (int d = 1; d < 7; ++d) { to0 += uf[12 - 2 * d] * w0[d]; to1 += uf[12 - 2 * d] * w1[d]; }
            te0 = (te0 >= 0.f ? te0 : 0.2f * te0) * SQ2;
            to0 = (to0 >= 0.f ? to0 : 0.2f * to0) * SQ2;
            te1 = (te1 >= 0.f ? te1 : 0.2f * te1) * SQ2;
            to1 = (to1 >= 0.f ? to1 : 0.2f * to1) * SQ2;
            tr0[5 + lane] = te0;      tr1[5 + lane] = to0;
            tr0[69 + lane] = te1;     tr1[69 + lane] = to1;
        }
        __builtin_amdgcn_wave_barrier();
        {
            int xo = lane;
            const float2* a0 = (const float2*)&tr0[2 * xo];
            const float2* a1 = (const float2*)&tr1[2 * xo];
            float v0[12], v1[12];
#pragma unroll
            for (int q = 0; q < 6; ++q) {
                float2 u0 = a0[q], u1 = a1[q];
                v0[2 * q] = u0.x; v0[2 * q + 1] = u0.y;
                v1[2 * q] = u1.x; v1[2 * q + 1] = u1.y;
            }
            float s0 = 0.f, s1 = 0.f;
#pragma unroll
            for (int u = 0; u < 12; ++u) {
                s0 += df[u] * v0[11 - u];
                s1 += df[u] * v1[11 - u];
            }
            bufB[(2 * n + 5) * 65 + xo] = s0;
            bufB[(2 * n + 6) * 65 + xo] = s1;
        }
        if (it < 15) {
#pragma unroll
            for (int d = 0; d < 3; ++d) { w0[d] = w0[d + 4]; w1[d] = w1[d + 4]; }
#pragma unroll
            for (int d = 3; d < 7; ++d) {
                w0[d] = bufA[(n + 4 + d) * 132 + lane];
                w1[d] = bufA[(n + 4 + d) * 132 + lane + 64];
            }
        }
        if ((it & 3) == 3) __syncthreads();
        else __builtin_amdgcn_wave_barrier();
    }
    for (int idx = tid; idx < 64 * 64; idx += 256) {
        int yo = idx >> 6, xx = idx & 63;
        float acc2 = 0.f;
#pragma unroll
        for (int u = 0; u < 12; ++u) {
            int rr = 2 * yo + 6 - u;
            float v = (rr < 128) ? bufB[(rr + 5) * 65 + xx] : 0.f;
            acc2 += df[u] * v;
        }
        dst[idx] = acc2;
    }
}

extern "C" void kernel_launch(void* const* d_in, const int* in_sizes, int n_in,
                              void* d_out, int out_size, void* d_ws, size_t ws_size,
                              hipStream_t stream) {
    const float* input       = (const float*)d_in[0];
    const float* style       = (const float*)d_in[1];
    const float* conv_weight = (const float*)d_in[2];
    const float* mod_w       = (const float*)d_in[3];
    const float* mod_b       = (const float*)d_in[4];
    const float* bias        = (const float*)d_in[5];
    const float* up_filter   = (const float*)d_in[6];
    const float* down_filter = (const float*)d_in[7];
    float* ws  = (float*)d_ws;
    float* out = (float*)d_out;
    float* s_buf   = ws;
    float* dm      = ws + 2048;
    float* wsq     = ws + 4096;
    unsigned short* wh      = (unsigned short*)(ws + 69632);
    float* zpage            = ws + 364544;
    unsigned short* xh      = (unsigned short*)(ws + 659456);
    unsigned short* convout = (unsigned short*)(ws + 9048064);

    hipLaunchKernelGGL(mod_kernel, dim3(512), dim3(256), 0, stream, style, mod_w, mod_b, s_buf, zpage);
    hipLaunchKernelGGL(wsplit_kernel, dim3(256), dim3(256), 0, stream, conv_weight, wsq, wh);
    hipLaunchKernelGGL(demod_kernel, dim3(512), dim3(256), 0, stream, s_buf, wsq, dm);
    hipLaunchKernelGGL(xsplit_kernel, dim3(512), dim3(256), 0, stream, input, s_buf, xh);
    hipLaunchKernelGGL(conv_mfma, dim3(32, 2, 8), dim3(256), 73728, stream,
                       xh, wh, (const unsigned short*)zpage, dm, bias, convout);
    hipLaunchKernelGGL(filter_kernel, dim3(2048), dim3(256), 0, stream,
                       convout, up_filter, down_filter, out);
}

// Round 18
// 118.153 us; speedup vs baseline: 1.1555x; 1.1555x over previous
//
#include <hip/hip_runtime.h>
#include <math.h>

#define B_   8
#define CIN  256
#define COUT 256
#define H_   64
#define W_   64
#define HO   62
#define WO   62
#define SDIM 512

// convout padded: [b][co][62][64] bf16 (cols 62,63 zeroed by conv epilogue)
#define CSTRIDE 64

typedef __attribute__((ext_vector_type(8))) short bf16x8;
typedef __attribute__((ext_vector_type(4))) float f32x4;

__device__ __forceinline__ unsigned short f2bf(float f) {
    unsigned int u = __float_as_uint(f);
    u += 0x7fffu + ((u >> 16) & 1u);
    return (unsigned short)(u >> 16);
}
__device__ __forceinline__ float bf2f(unsigned short h) {
    return __uint_as_float(((unsigned int)h) << 16);
}

// ws layout (floats):
// s:       [0, 2048)
// dm:      [2048, 4096)
// wsq:     [4096, 69632)
// wh:      [69632, 364544)     (9*256*256 ushort, hi only)
// zpage:   [364544, 365056)    (512 floats, zeroed by mod_kernel each launch)
// xh:      [659456, 4853760)   (8*64*64*256 ushort)
// convout: [9048064, 13111296) (8*256*62*64 ushort)

__global__ void mod_kernel(const float* __restrict__ style, const float* __restrict__ mod_w,
                           const float* __restrict__ mod_b, float* __restrict__ s_out,
                           float* __restrict__ zpage) {
    if (blockIdx.x == 0) {
        zpage[threadIdx.x] = 0.f;
        zpage[threadIdx.x + 256] = 0.f;
    }
    int wid = blockIdx.x * 4 + (threadIdx.x >> 6);
    int lane = threadIdx.x & 63;
    int b = wid >> 8, ci = wid & 255;
    float acc = 0.f;
    const float* st = style + b * SDIM;
    const float* mw = mod_w + ci * SDIM;
    for (int i = 0; i < SDIM; i += 64) acc += st[i + lane] * mw[i + lane];
    for (int m = 32; m >= 1; m >>= 1) acc += __shfl_xor(acc, m, 64);
    if (lane == 0) s_out[wid] = acc * 0.04419417382415922f + mod_b[ci]; // 1/sqrt(512)
}

__global__ void wsplit_kernel(const float* __restrict__ cw, float* __restrict__ wsq,
                              unsigned short* __restrict__ wh) {
    int idx = blockIdx.x * blockDim.x + threadIdx.x; // co*256+ci
    int co = idx >> 8, ci = idx & 255;
    const float* p = cw + (size_t)idx * 9;
    float ss = 0.f;
#pragma unroll
    for (int k = 0; k < 9; ++k) {
        float v = p[k];
        ss += v * v;
        wh[(k * COUT + co) * CIN + ci] = f2bf(v);
    }
    wsq[idx] = ss;
}

__global__ void demod_kernel(const float* __restrict__ s_in, const float* __restrict__ wsq,
                             float* __restrict__ dm) {
    int wid = blockIdx.x * 4 + (threadIdx.x >> 6);
    int lane = threadIdx.x & 63;
    int b = wid >> 8, co = wid & 255;
    float acc = 0.f;
    for (int i = 0; i < CIN; i += 64) {
        float sv = s_in[b * CIN + i + lane];
        acc += sv * sv * wsq[co * CIN + i + lane];
    }
    for (int m = 32; m >= 1; m >>= 1) acc += __shfl_xor(acc, m, 64);
    if (lane == 0) {
        const float scale = 0.020833333333333332f; // 1/48 = 1/sqrt(2304)
        float demod = rsqrtf(scale * scale * acc + 1e-8f);
        dm[wid] = demod * scale / (1.f + 1e-8f);
    }
}

// Transpose+scale: x[b][ci][y][x] f32 -> xh[b][y][x][ci] bf16.
__global__ __launch_bounds__(256) void xsplit_kernel(
        const float* __restrict__ x, const float* __restrict__ s_in,
        unsigned short* __restrict__ xh) {
    __shared__ float tile[128 * 65];
    __shared__ float s_loc[256];
    int b = blockIdx.x >> 6;
    int y = blockIdx.x & 63;
    int tid = threadIdx.x;
    s_loc[tid] = s_in[(b << 8) + tid];
    __syncthreads();
    for (int half = 0; half < 2; ++half) {
        int cb = half << 7;
        for (int f = tid; f < 2048; f += 256) {
            int ci = f >> 4, x4 = (f & 15) << 2;
            float4 v = *(const float4*)(x + ((((size_t)b << 8) + cb + ci) << 12) + (y << 6) + x4);
            float sv = s_loc[cb + ci];
            float* t = tile + ci * 65 + x4;
            t[0] = v.x * sv; t[1] = v.y * sv; t[2] = v.z * sv; t[3] = v.w * sv;
        }
        __syncthreads();
        for (int g = tid; g < 1024; g += 256) {
            int c = g & 15, xx = g >> 4;   // c: 8-ci chunk, xx: x position
            unsigned int hw[4];
#pragma unroll
            for (int q = 0; q < 4; ++q) {
                float v0 = tile[(c * 8 + 2 * q) * 65 + xx];
                float v1 = tile[(c * 8 + 2 * q + 1) * 65 + xx];
                hw[q] = (unsigned int)f2bf(v0) | ((unsigned int)f2bf(v1) << 16);
            }
            int o = ((((b << 6) + y) << 6) + xx) * 256 + cb + (c << 3);
            *(uint4*)(xh + o) = make_uint4(hw[0], hw[1], hw[2], hw[3]);
        }
        __syncthreads();
    }
}

// DMA staging helpers (global_load_lds, width 16): linear LDS dest, source
// carries the XOR bank-swizzle (pre-swizzled-source pattern).
__device__ __forceinline__ void stage_b(const unsigned short* wh, const int* bsrc,
                                        short* dst, int tid, int kyci) {
#pragma unroll
    for (int j = 0; j < 6; ++j)
        __builtin_amdgcn_global_load_lds(
            (const __attribute__((address_space(1))) unsigned int*)(wh + bsrc[j] + kyci),
            (__attribute__((address_space(3))) unsigned int*)(dst + ((tid + (j << 8)) << 3)),
            16, 0, 0);
}
__device__ __forceinline__ void stage_a(const unsigned short* a0, const unsigned short* a1,
                                        const unsigned short* a2, short* dst, int tid, int ci0) {
    __builtin_amdgcn_global_load_lds(
        (const __attribute__((address_space(1))) unsigned int*)(a0 + ci0),
        (__attribute__((address_space(3))) unsigned int*)(dst + (tid << 3)), 16, 0, 0);
    __builtin_amdgcn_global_load_lds(
        (const __attribute__((address_space(1))) unsigned int*)(a1 + ci0),
        (__attribute__((address_space(3))) unsigned int*)(dst + ((tid + 256) << 3)), 16, 0, 0);
    __builtin_amdgcn_global_load_lds(
        (const __attribute__((address_space(1))) unsigned int*)(a2 + ci0),
        (__attribute__((address_space(3))) unsigned int*)(dst + ((tid + 512) << 3)), 16, 0, 0);
}

// compute one ky-phase (static KY): 3 kx * 4 nt * 4 yr MFMAs (hi-only)
template<int KY>
__device__ __forceinline__ void conv_compute(const short* Ah, const short* Bb,
        f32x4 (&acc)[4][4], int lrow, int lch, int wy, int wc) {
#pragma unroll
    for (int kx = 0; kx < 3; ++kx) {
        int colL = lrow + kx;
        int asw = (lch ^ ((colL >> 1) & 3)) << 3;
        bf16x8 ahf[4];
#pragma unroll
        for (int yr = 0; yr < 4; ++yr) {
            int rr = wy * 4 + yr + KY;
            ahf[yr] = *(const bf16x8*)(Ah + (rr * 18 + colL) * 32 + asw);
        }
#pragma unroll
        for (int nt = 0; nt < 4; ++nt) {
            int col = wc * 64 + nt * 16 + lrow;
            int boff = (kx << 12) + (col << 5) + ((lch ^ ((col >> 1) & 3)) << 3);
            bf16x8 bhf = *(const bf16x8*)(Bb + boff);
#pragma unroll
            for (int yr = 0; yr < 4; ++yr)
                acc[yr][nt] = __builtin_amdgcn_mfma_f32_16x16x32_bf16(ahf[yr], bhf, acc[yr][nt], 0, 0, 0);
        }
    }
}

// Implicit-GEMM modulated conv, single-pass bf16 MFMA (ah*bh), async
// double-buffered staging via global_load_lds (no VGPR round-trip).
// LDS: A0/A1 768 slots, B0/B1 1536 slots, 16B each = 73728 B -> 2 blocks/CU.
__global__ __launch_bounds__(256) void conv_mfma(
        const unsigned short* __restrict__ xh,
        const unsigned short* __restrict__ wh,
        const unsigned short* __restrict__ zpage,
        const float* __restrict__ dm,
        const float* __restrict__ bias, unsigned short* __restrict__ convout) {
    extern __shared__ short lds[];

    int tid = threadIdx.x;
    int b = blockIdx.z;
    int co0 = blockIdx.y << 7;
    int sx = blockIdx.x & 3, sy = blockIdx.x >> 2;
    int x0 = sx << 4, y0 = sy << 3;
    int wid = tid >> 6, lane = tid & 63;
    int wy = wid >> 1, wc = wid & 1;
    int lrow = lane & 15, lch = lane >> 4;

    int bsrc[6];
#pragma unroll
    for (int j = 0; j < 6; ++j) {
        int u = tid + (j << 8);
        int chunk = u & 3;
        int co = (u >> 2) & 127;
        int kx = u >> 9;
        int cs = chunk ^ ((co >> 1) & 3);
        bsrc[j] = (kx << 16) + ((co0 + co) << 8) + (cs << 3);
    }
    const unsigned short* ap0;
    const unsigned short* ap1;
    const unsigned short* ap2;
#pragma unroll
    for (int k = 0; k < 3; ++k) {
        int u = tid + (k << 8);
        int t2 = u >> 2;
        int col = t2 % 18, row = t2 / 18;
        int yy = y0 + row, xx = x0 + col;
        bool ok = (u < 720) && (yy < 64) && (xx < 64);
        int cs = (u & 3) ^ ((col >> 1) & 3);
        const unsigned short* p = ok ? xh + ((((b << 6) + yy) << 6) + xx) * 256 + (cs << 3) : zpage;
        if (k == 0) ap0 = p; else if (k == 1) ap1 = p; else ap2 = p;
    }

    f32x4 acc[4][4];
#pragma unroll
    for (int i = 0; i < 4; ++i)
#pragma unroll
        for (int j = 0; j < 4; ++j) acc[i][j] = (f32x4){0.f, 0.f, 0.f, 0.f};

    stage_a(ap0, ap1, ap2, lds, tid, 0);
    stage_b(wh, bsrc, lds + 12288, tid, 0);
    __syncthreads();

#pragma unroll 1
    for (int ks = 0; ks < 8; ++ks) {
        int ci0 = ks << 5;
        int ci0n = (ks + 1) << 5;   // ks=7: harmless garbage prefetch, never read
        int pb = ks & 1;
        short* Acur = lds + (pb ? 6144 : 0);
        short* Anxt = lds + (pb ? 0 : 6144);
        short* Bcur = lds + (pb ? 24576 : 12288);
        short* Balt = lds + (pb ? 12288 : 24576);
        stage_b(wh, bsrc, Balt, tid, 196608 + ci0);
        conv_compute<0>(Acur, Bcur, acc, lrow, lch, wy, wc);
        __syncthreads();
        stage_b(wh, bsrc, Bcur, tid, 2 * 196608 + ci0);
        conv_compute<1>(Acur, Balt, acc, lrow, lch, wy, wc);
        __syncthreads();
        stage_b(wh, bsrc, Balt, tid, ci0n);
        stage_a(ap0, ap1, ap2, Anxt, tid, ci0n);
        conv_compute<2>(Acur, Bcur, acc, lrow, lch, wy, wc);
        __syncthreads();
    }

    // epilogue: D row = x-pos = 4*lch + j, D col = co = 16*nt + lrow.
    // Cols 62,63 (xs4==60, z/w elements) are zeroed so filter's unguarded
    // global reads see clean right-padding.
    int xs4 = x0 + (lch << 2);
#pragma unroll
    for (int nt = 0; nt < 4; ++nt) {
        int co = co0 + wc * 64 + nt * 16 + lrow;
        float dmv = dm[(b << 8) + co];
        float bv = bias[co];
#pragma unroll
        for (int yr = 0; yr < 4; ++yr) {
            int y = y0 + wy * 4 + yr;
            if (y < HO) {
                ushort4 o;
                o.x = f2bf(acc[yr][nt][0] * dmv + bv);
                o.y = f2bf(acc[yr][nt][1] * dmv + bv);
                o.z = f2bf(acc[yr][nt][2] * dmv + bv);
                o.w = f2bf(acc[yr][nt][3] * dmv + bv);
                if (xs4 == 60) { o.z = 0; o.w = 0; }
                *(ushort4*)(convout + ((size_t)((b << 8) + co) * HO + y) * CSTRIDE + xs4) = o;
            }
        }
    }
}

// Fused upfirdn chain per (b,c) plane. 62x62 bf16 in -> 64x64 f32 out.
// lds0 (floats): bufA [2432, 11672) 70 rows stride 132 (+4 row offset, pads 0)
//                bufB [0, 8970) 138 rows stride 65 (+5 row offset), aliases bufA
// up-x reads convout DIRECTLY from global (no cin LDS stage).
// BARRIER DISCIPLINE (r16/r17 bug): uf/df are written by threads 0..11 and
// read by ALL threads in up-x -> a __syncthreads() MUST sit between init and
// up-x (r15 had one implicitly via the cin stage; removing cin dropped it).
// Aliasing safety with barrier every 4 its (window W = its 4W..4W+3):
//  Window 0: initial register-window loads (bufA rows 0..9, from float 2432)
//  retire at END-of-window-0 barrier; window-0 bufB writes reach
//  (32*0+36)*65+63 = 2403 <= 2432 = bufA base. For all rows r: first bufB
//  write touching bufA row r lands >= 1 full window after r's last LDS read
//  (W_write - W_read >= 1, slack grows with r). bufB pad [0,325) < 2432.
__global__ __launch_bounds__(256) void filter_kernel(
        const unsigned short* __restrict__ convout, const float* __restrict__ upf,
        const float* __restrict__ dnf, float* __restrict__ out) {
    __shared__ __align__(16) float lds0[11672];
    __shared__ __align__(16) float trow2[4][2][144];
    __shared__ float uf[12], df[12];
    float* bufA = lds0 + 2432;
    float* bufB = lds0;
    int tid = threadIdx.x;
    int p = blockIdx.x;
    const unsigned short* src = convout + (size_t)p * (HO * CSTRIDE);
    float* dst = out + (size_t)p * (64 * 64);
    // phase 0: filter taps + pad zeroing (no shared reads yet)
    if (tid < 12) { uf[tid] = upf[tid] * 2.f; df[tid] = dnf[tid]; }
    for (int idx = tid; idx < 1056; idx += 256) {
        int r = idx / 132, cc = idx - r * 132;
        bufA[(r < 4 ? r : 62 + r) * 132 + cc] = 0.f;
    }
    for (int idx = tid; idx < 325; idx += 256) bufB[idx] = 0.f;
    __syncthreads();   // uf/df + pads visible before any read (r16/r17 fix)
    // phase 1: up-x from global, writes bufA rows 4..65
    for (int task = tid; task < 62 * 16; task += 256) {
        int y = task >> 4, g = task & 15;
        const unsigned short* row = src + y * CSTRIDE + (g << 2);
        ushort4 c0 = (g > 0)  ? *(const ushort4*)(row - 4) : make_ushort4(0, 0, 0, 0);
        ushort4 c1 = *(const ushort4*)(row);
        ushort4 c2 = (g < 15) ? *(const ushort4*)(row + 4) : make_ushort4(0, 0, 0, 0);
        float xv[10];
        xv[0] = bf2f(c0.x); xv[1] = bf2f(c0.y); xv[2] = bf2f(c0.z); xv[3] = bf2f(c0.w);
        xv[4] = bf2f(c1.x); xv[5] = bf2f(c1.y); xv[6] = bf2f(c1.z); xv[7] = bf2f(c1.w);
        xv[8] = bf2f(c2.x); xv[9] = bf2f(c2.y);
        float* arow = bufA + (y + 4) * 132 + (g << 3);
#pragma unroll
        for (int dd = 0; dd < 4; ++dd) {
            float oe = 0.f, oo = 0.f;
#pragma unroll
            for (int v = 0; v < 6; ++v) {
                oe += uf[2 * v + 1] * xv[dd + 5 - v];
                oo += uf[2 * v] * xv[dd + 6 - v];
            }
            *(float2*)(arow + 2 * dd) = make_float2(oe, oo);
        }
    }
    __syncthreads();

    int wid = tid >> 6, lane = tid & 63;
    float* tr0 = &trow2[wid][0][0];
    float* tr1 = &trow2[wid][1][0];
    if (lane < 5) { tr0[lane] = 0.f; tr1[lane] = 0.f; }
    if (lane < 7) { tr0[133 + lane] = 0.f; tr1[133 + lane] = 0.f; }
    const float SQ2 = 1.4142135623730951f;
    float w0[7], w1[7];
#pragma unroll
    for (int d = 0; d < 7; ++d) {
        w0[d] = bufA[(wid + d) * 132 + lane];
        w1[d] = bufA[(wid + d) * 132 + lane + 64];
    }
    for (int it = 0; it < 16; ++it) {
        int n = 4 * it + wid;
        {
            float te0 = 0.f, to0 = 0.f, te1 = 0.f, to1 = 0.f;
#pragma unroll
            for (int d = 0; d < 6; ++d) { te0 += uf[11 - 2 * d] * w0[d]; te1 += uf[11 - 2 * d] * w1[d]; }
#pragma unroll
            for (int d = 1; d < 7; ++d) { to0 += uf[12 - 2 * d] * w0[d]; to1 += uf[12 - 2 * d] * w1[d]; }
            te0 = (te0 >= 0.f ? te0 : 0.2f * te0) * SQ2;
            to0 = (to0 >= 0.f ? to0 : 0.2f * to0) * SQ2;
            te1 = (te1 >= 0.f ? te1 : 0.2f * te1) * SQ2;
            to1 = (to1 >= 0.f ? to1 : 0.2f * to1) * SQ2;
            tr0[5 + lane] = te0;      tr1[5 + lane] = to0;
            tr0[69 + lane] = te1;     tr1[69 + lane] = to1;
        }
        __builtin_amdgcn_wave_barrier();
        {
            int xo = lane;
            const float2* a0 = (const float2*)&tr0[2 * xo];
            const float2* a1 = (const float2*)&tr1[2 * xo];
            float v0[12], v1[12];
#pragma unroll
            for (int q = 0; q < 6; ++q) {
                float2 u0 = a0[q], u1 = a1[q];
                v0[2 * q] = u0.x; v0[2 * q + 1] = u0.y;
                v1[2 * q] = u1.x; v1[2 * q + 1] = u1.y;
            }
            float s0 = 0.f, s1 = 0.f;
#pragma unroll
            for (int u = 0; u < 12; ++u) {
                s0 += df[u] * v0[11 - u];
                s1 += df[u] * v1[11 - u];
            }
            bufB[(2 * n + 5) * 65 + xo] = s0;
            bufB[(2 * n + 6) * 65 + xo] = s1;
        }
        if (it < 15) {
#pragma unroll
            for (int d = 0; d < 3; ++d) { w0[d] = w0[d + 4]; w1[d] = w1[d + 4]; }
#pragma unroll
            for (int d = 3; d < 7; ++d) {
                w0[d] = bufA[(n + 4 + d) * 132 + lane];
                w1[d] = bufA[(n + 4 + d) * 132 + lane + 64];
            }
        }
        if ((it & 3) == 3) __syncthreads();
        else __builtin_amdgcn_wave_barrier();
    }
    for (int idx = tid; idx < 64 * 64; idx += 256) {
        int yo = idx >> 6, xx = idx & 63;
        float acc2 = 0.f;
#pragma unroll
        for (int u = 0; u < 12; ++u) {
            int rr = 2 * yo + 6 - u;
            float v = (rr < 128) ? bufB[(rr + 5) * 65 + xx] : 0.f;
            acc2 += df[u] * v;
        }
        dst[idx] = acc2;
    }
}

extern "C" void kernel_launch(void* const* d_in, const int* in_sizes, int n_in,
                              void* d_out, int out_size, void* d_ws, size_t ws_size,
                              hipStream_t stream) {
    const float* input       = (const float*)d_in[0];
    const float* style       = (const float*)d_in[1];
    const float* conv_weight = (const float*)d_in[2];
    const float* mod_w       = (const float*)d_in[3];
    const float* mod_b       = (const float*)d_in[4];
    const float* bias        = (const float*)d_in[5];
    const float* up_filter   = (const float*)d_in[6];
    const float* down_filter = (const float*)d_in[7];
    float* ws  = (float*)d_ws;
    float* out = (float*)d_out;
    float* s_buf   = ws;
    float* dm      = ws + 2048;
    float* wsq     = ws + 4096;
    unsigned short* wh      = (unsigned short*)(ws + 69632);
    float* zpage            = ws + 364544;
    unsigned short* xh      = (unsigned short*)(ws + 659456);
    unsigned short* convout = (unsigned short*)(ws + 9048064);

    hipLaunchKernelGGL(mod_kernel, dim3(512), dim3(256), 0, stream, style, mod_w, mod_b, s_buf, zpage);
    hipLaunchKernelGGL(wsplit_kernel, dim3(256), dim3(256), 0, stream, conv_weight, wsq, wh);
    hipLaunchKernelGGL(demod_kernel, dim3(512), dim3(256), 0, stream, s_buf, wsq, dm);
    hipLaunchKernelGGL(xsplit_kernel, dim3(512), dim3(256), 0, stream, input, s_buf, xh);
    hipLaunchKernelGGL(conv_mfma, dim3(32, 2, 8), dim3(256), 73728, stream,
                       xh, wh, (const unsigned short*)zpage, dm, bias, convout);
    hipLaunchKernelGGL(filter_kernel, dim3(2048), dim3(256), 0, stream,
                       convout, up_filter, down_filter, out);
}

// Round 19
// 104.833 us; speedup vs baseline: 1.3024x; 1.1271x over previous
//
#include <hip/hip_runtime.h>
#include <math.h>

#define B_   8
#define CIN  256
#define COUT 256
#define H_   64
#define W_   64
#define HO   62
#define WO   62
#define SDIM 512

// convout padded: [b][co][62][64] bf16 (cols 62,63 zeroed by conv epilogue)
#define CSTRIDE 64

typedef __attribute__((ext_vector_type(8))) short bf16x8;
typedef __attribute__((ext_vector_type(4))) float f32x4;

__device__ __forceinline__ unsigned short f2bf(float f) {
    unsigned int u = __float_as_uint(f);
    u += 0x7fffu + ((u >> 16) & 1u);
    return (unsigned short)(u >> 16);
}
__device__ __forceinline__ float bf2f(unsigned short h) {
    return __uint_as_float(((unsigned int)h) << 16);
}

// ws layout (floats):
// s:       [0, 2048)
// dm:      [2048, 4096)
// wsq:     [4096, 69632)
// wh:      [69632, 364544)     (9*256*256 ushort, hi only)
// zpage:   [364544, 365056)    (512 floats, zeroed by mod_kernel each launch)
// xh:      [659456, 4853760)   (8*64*64*256 ushort)
// convout: [9048064, 13111296) (8*256*62*64 ushort)

__global__ void mod_kernel(const float* __restrict__ style, const float* __restrict__ mod_w,
                           const float* __restrict__ mod_b, float* __restrict__ s_out,
                           float* __restrict__ zpage) {
    if (blockIdx.x == 0) {
        zpage[threadIdx.x] = 0.f;
        zpage[threadIdx.x + 256] = 0.f;
    }
    int wid = blockIdx.x * 4 + (threadIdx.x >> 6);
    int lane = threadIdx.x & 63;
    int b = wid >> 8, ci = wid & 255;
    float acc = 0.f;
    const float* st = style + b * SDIM;
    const float* mw = mod_w + ci * SDIM;
    for (int i = 0; i < SDIM; i += 64) acc += st[i + lane] * mw[i + lane];
    for (int m = 32; m >= 1; m >>= 1) acc += __shfl_xor(acc, m, 64);
    if (lane == 0) s_out[wid] = acc * 0.04419417382415922f + mod_b[ci]; // 1/sqrt(512)
}

__global__ void wsplit_kernel(const float* __restrict__ cw, float* __restrict__ wsq,
                              unsigned short* __restrict__ wh) {
    int idx = blockIdx.x * blockDim.x + threadIdx.x; // co*256+ci
    int co = idx >> 8, ci = idx & 255;
    const float* p = cw + (size_t)idx * 9;
    float ss = 0.f;
#pragma unroll
    for (int k = 0; k < 9; ++k) {
        float v = p[k];
        ss += v * v;
        wh[(k * COUT + co) * CIN + ci] = f2bf(v);
    }
    wsq[idx] = ss;
}

__global__ void demod_kernel(const float* __restrict__ s_in, const float* __restrict__ wsq,
                             float* __restrict__ dm) {
    int wid = blockIdx.x * 4 + (threadIdx.x >> 6);
    int lane = threadIdx.x & 63;
    int b = wid >> 8, co = wid & 255;
    float acc = 0.f;
    for (int i = 0; i < CIN; i += 64) {
        float sv = s_in[b * CIN + i + lane];
        acc += sv * sv * wsq[co * CIN + i + lane];
    }
    for (int m = 32; m >= 1; m >>= 1) acc += __shfl_xor(acc, m, 64);
    if (lane == 0) {
        const float scale = 0.020833333333333332f; // 1/48 = 1/sqrt(2304)
        float demod = rsqrtf(scale * scale * acc + 1e-8f);
        dm[wid] = demod * scale / (1.f + 1e-8f);
    }
}

// Transpose+scale: x[b][ci][y][x] f32 -> xh[b][y][x][ci] bf16.
__global__ __launch_bounds__(256) void xsplit_kernel(
        const float* __restrict__ x, const float* __restrict__ s_in,
        unsigned short* __restrict__ xh) {
    __shared__ float tile[128 * 65];
    __shared__ float s_loc[256];
    int b = blockIdx.x >> 6;
    int y = blockIdx.x & 63;
    int tid = threadIdx.x;
    s_loc[tid] = s_in[(b << 8) + tid];
    __syncthreads();
    for (int half = 0; half < 2; ++half) {
        int cb = half << 7;
        for (int f = tid; f < 2048; f += 256) {
            int ci = f >> 4, x4 = (f & 15) << 2;
            float4 v = *(const float4*)(x + ((((size_t)b << 8) + cb + ci) << 12) + (y << 6) + x4);
            float sv = s_loc[cb + ci];
            float* t = tile + ci * 65 + x4;
            t[0] = v.x * sv; t[1] = v.y * sv; t[2] = v.z * sv; t[3] = v.w * sv;
        }
        __syncthreads();
        for (int g = tid; g < 1024; g += 256) {
            int c = g & 15, xx = g >> 4;   // c: 8-ci chunk, xx: x position
            unsigned int hw[4];
#pragma unroll
            for (int q = 0; q < 4; ++q) {
                float v0 = tile[(c * 8 + 2 * q) * 65 + xx];
                float v1 = tile[(c * 8 + 2 * q + 1) * 65 + xx];
                hw[q] = (unsigned int)f2bf(v0) | ((unsigned int)f2bf(v1) << 16);
            }
            int o = ((((b << 6) + y) << 6) + xx) * 256 + cb + (c << 3);
            *(uint4*)(xh + o) = make_uint4(hw[0], hw[1], hw[2], hw[3]);
        }
        __syncthreads();
    }
}

// DMA staging helpers (global_load_lds, width 16): linear LDS dest, source
// carries the XOR bank-swizzle (pre-swizzled-source pattern).
__device__ __forceinline__ void stage_b(const unsigned short* wh, const int* bsrc,
                                        short* dst, int tid, int kyci) {
#pragma unroll
    for (int j = 0; j < 6; ++j)
        __builtin_amdgcn_global_load_lds(
            (const __attribute__((address_space(1))) unsigned int*)(wh + bsrc[j] + kyci),
            (__attribute__((address_space(3))) unsigned int*)(dst + ((tid + (j << 8)) << 3)),
            16, 0, 0);
}
__device__ __forceinline__ void stage_a(const unsigned short* a0, const unsigned short* a1,
                                        const unsigned short* a2, short* dst, int tid, int ci0) {
    __builtin_amdgcn_global_load_lds(
        (const __attribute__((address_space(1))) unsigned int*)(a0 + ci0),
        (__attribute__((address_space(3))) unsigned int*)(dst + (tid << 3)), 16, 0, 0);
    __builtin_amdgcn_global_load_lds(
        (const __attribute__((address_space(1))) unsigned int*)(a1 + ci0),
        (__attribute__((address_space(3))) unsigned int*)(dst + ((tid + 256) << 3)), 16, 0, 0);
    __builtin_amdgcn_global_load_lds(
        (const __attribute__((address_space(1))) unsigned int*)(a2 + ci0),
        (__attribute__((address_space(3))) unsigned int*)(dst + ((tid + 512) << 3)), 16, 0, 0);
}

// compute one ky-phase (static KY): 3 kx * 4 nt * 4 yr MFMAs (hi-only)
template<int KY>
__device__ __forceinline__ void conv_compute(const short* Ah, const short* Bb,
        f32x4 (&acc)[4][4], int lrow, int lch, int wy, int wc) {
#pragma unroll
    for (int kx = 0; kx < 3; ++kx) {
        int colL = lrow + kx;
        int asw = (lch ^ ((colL >> 1) & 3)) << 3;
        bf16x8 ahf[4];
#pragma unroll
        for (int yr = 0; yr < 4; ++yr) {
            int rr = wy * 4 + yr + KY;
            ahf[yr] = *(const bf16x8*)(Ah + (rr * 18 + colL) * 32 + asw);
        }
#pragma unroll
        for (int nt = 0; nt < 4; ++nt) {
            int col = wc * 64 + nt * 16 + lrow;
            int boff = (kx << 12) + (col << 5) + ((lch ^ ((col >> 1) & 3)) << 3);
            bf16x8 bhf = *(const bf16x8*)(Bb + boff);
#pragma unroll
            for (int yr = 0; yr < 4; ++yr)
                acc[yr][nt] = __builtin_amdgcn_mfma_f32_16x16x32_bf16(ahf[yr], bhf, acc[yr][nt], 0, 0, 0);
        }
    }
}

// Implicit-GEMM modulated conv, single-pass bf16 MFMA (ah*bh), async
// double-buffered staging via global_load_lds (no VGPR round-trip).
// LDS: A0/A1 768 slots, B0/B1 1536 slots, 16B each = 73728 B -> 2 blocks/CU.
__global__ __launch_bounds__(256) void conv_mfma(
        const unsigned short* __restrict__ xh,
        const unsigned short* __restrict__ wh,
        const unsigned short* __restrict__ zpage,
        const float* __restrict__ dm,
        const float* __restrict__ bias, unsigned short* __restrict__ convout) {
    extern __shared__ short lds[];

    int tid = threadIdx.x;
    int b = blockIdx.z;
    int co0 = blockIdx.y << 7;
    int sx = blockIdx.x & 3, sy = blockIdx.x >> 2;
    int x0 = sx << 4, y0 = sy << 3;
    int wid = tid >> 6, lane = tid & 63;
    int wy = wid >> 1, wc = wid & 1;
    int lrow = lane & 15, lch = lane >> 4;

    int bsrc[6];
#pragma unroll
    for (int j = 0; j < 6; ++j) {
        int u = tid + (j << 8);
        int chunk = u & 3;
        int co = (u >> 2) & 127;
        int kx = u >> 9;
        int cs = chunk ^ ((co >> 1) & 3);
        bsrc[j] = (kx << 16) + ((co0 + co) << 8) + (cs << 3);
    }
    const unsigned short* ap0;
    const unsigned short* ap1;
    const unsigned short* ap2;
#pragma unroll
    for (int k = 0; k < 3; ++k) {
        int u = tid + (k << 8);
        int t2 = u >> 2;
        int col = t2 % 18, row = t2 / 18;
        int yy = y0 + row, xx = x0 + col;
        bool ok = (u < 720) && (yy < 64) && (xx < 64);
        int cs = (u & 3) ^ ((col >> 1) & 3);
        const unsigned short* p = ok ? xh + ((((b << 6) + yy) << 6) + xx) * 256 + (cs << 3) : zpage;
        if (k == 0) ap0 = p; else if (k == 1) ap1 = p; else ap2 = p;
    }

    f32x4 acc[4][4];
#pragma unroll
    for (int i = 0; i < 4; ++i)
#pragma unroll
        for (int j = 0; j < 4; ++j) acc[i][j] = (f32x4){0.f, 0.f, 0.f, 0.f};

    stage_a(ap0, ap1, ap2, lds, tid, 0);
    stage_b(wh, bsrc, lds + 12288, tid, 0);
    __syncthreads();

#pragma unroll 1
    for (int ks = 0; ks < 8; ++ks) {
        int ci0 = ks << 5;
        int ci0n = (ks + 1) << 5;   // ks=7: harmless garbage prefetch, never read
        int pb = ks & 1;
        short* Acur = lds + (pb ? 6144 : 0);
        short* Anxt = lds + (pb ? 0 : 6144);
        short* Bcur = lds + (pb ? 24576 : 12288);
        short* Balt = lds + (pb ? 12288 : 24576);
        stage_b(wh, bsrc, Balt, tid, 196608 + ci0);
        conv_compute<0>(Acur, Bcur, acc, lrow, lch, wy, wc);
        __syncthreads();
        stage_b(wh, bsrc, Bcur, tid, 2 * 196608 + ci0);
        conv_compute<1>(Acur, Balt, acc, lrow, lch, wy, wc);
        __syncthreads();
        stage_b(wh, bsrc, Balt, tid, ci0n);
        stage_a(ap0, ap1, ap2, Anxt, tid, ci0n);
        conv_compute<2>(Acur, Bcur, acc, lrow, lch, wy, wc);
        __syncthreads();
    }

    // epilogue: D row = x-pos = 4*lch + j, D col = co = 16*nt + lrow.
    // Cols 62,63 (xs4==60, z/w elements) are zeroed so filter's unguarded
    // global reads see clean right-padding.
    int xs4 = x0 + (lch << 2);
#pragma unroll
    for (int nt = 0; nt < 4; ++nt) {
        int co = co0 + wc * 64 + nt * 16 + lrow;
        float dmv = dm[(b << 8) + co];
        float bv = bias[co];
#pragma unroll
        for (int yr = 0; yr < 4; ++yr) {
            int y = y0 + wy * 4 + yr;
            if (y < HO) {
                ushort4 o;
                o.x = f2bf(acc[yr][nt][0] * dmv + bv);
                o.y = f2bf(acc[yr][nt][1] * dmv + bv);
                o.z = f2bf(acc[yr][nt][2] * dmv + bv);
                o.w = f2bf(acc[yr][nt][3] * dmv + bv);
                if (xs4 == 60) { o.z = 0; o.w = 0; }
                *(ushort4*)(convout + ((size_t)((b << 8) + co) * HO + y) * CSTRIDE + xs4) = o;
            }
        }
    }
}

// Vertical pipeline: up-y + leaky + down-y for one column c, rows h-half.
// Register-resident: bufA sliding window w[7] (+2-deep prefetch), 13-deep
// t-ring with compile-time modular indices (full unroll -> registers, rule #20).
// Pair n produces t rows 2n,2n+1 (rows >=128 are zero-pad); output yo emitted
// at n = yo+3 from t rows 2n-11..2n. Initial t zeros cover negative rows
// (their ring slots 8..12 are first written at n>=4, after the early emits
// read them). bufA rows clamp at 69 (zero pads); clamped loads feed only
// dead (zeroed) pairs.
template<int N0, int NSTEPS, int KSTART>
__device__ __forceinline__ void vpipe(const float* __restrict__ bufA,
                                      float* __restrict__ C, int c,
                                      const float* __restrict__ uf,
                                      const float* __restrict__ df) {
    const float SQ2 = 1.4142135623730951f;
    float ufr[12], dfr[12];
#pragma unroll
    for (int i = 0; i < 12; ++i) { ufr[i] = uf[i]; dfr[i] = df[i]; }
    float w[7];
#pragma unroll
    for (int d = 0; d < 7; ++d) w[d] = bufA[(N0 + d) * 132 + c];
    float pcur = bufA[((N0 + 7) > 69 ? 69 : (N0 + 7)) * 132 + c];
    float t[13];
#pragma unroll
    for (int i = 0; i < 13; ++i) t[i] = 0.f;
#pragma unroll
    for (int k = 0; k < NSTEPS; ++k) {
        const int n = N0 + k;
        const int rnext = (n + 8) > 69 ? 69 : (n + 8);
        float pnext = bufA[rnext * 132 + c];           // issued early, used next step
        float te = 0.f, to = 0.f;
#pragma unroll
        for (int d = 0; d < 6; ++d) te += ufr[11 - 2 * d] * w[d];
#pragma unroll
        for (int d = 1; d < 7; ++d) to += ufr[12 - 2 * d] * w[d];
        te = (te >= 0.f ? te : 0.2f * te) * SQ2;
        to = (to >= 0.f ? to : 0.2f * to) * SQ2;
        if (2 * n < 128) {
            t[(2 * n) % 13] = te;
            t[(2 * n + 1) % 13] = to;
        } else {
            t[(2 * n) % 13] = 0.f;
            t[(2 * n + 1) % 13] = 0.f;
        }
        if (k >= KSTART) {
            const int yo = n - 3;
            float acc = 0.f;
#pragma unroll
            for (int u = 0; u < 12; ++u) {
                const int r = 2 * n - u;               // = 2*yo+6-u
                const int ri = ((r % 13) + 13) % 13;   // compile-time
                acc += dfr[u] * t[ri];
            }
            C[yo * 140 + 5 + c] = acc;
        }
#pragma unroll
        for (int d = 0; d < 6; ++d) w[d] = w[d + 1];
        w[6] = pcur;
        pcur = pnext;
    }
}

// Fused upfirdn chain per (b,c) plane. 62x62 bf16 in -> 64x64 f32 out.
// Chain reordered via commutativity: up-x -> up-y -> leaky -> DOWN-Y -> DOWN-X
// (down-x/down-y are linear on different axes). Middle section is vertical-only
// -> per-column register pipeline, NO barriers, no tr round-trips (r18's cost).
// lds0: bufA [0, 9240) 70 rows stride 132 (rows 4..65 data, pads zeroed);
//       C    [9240, 18200) 64 rows stride 140 (i = 5+c, c=0..127 data;
//             i 0..4 and 133..137 zero pads for the down-x window).
// 256 threads = 128 columns x 2 row-halves: h=0 emits yo 0..31 (n=0..34),
// h=1 emits yo 32..63 (n=29..66, 6 warm-up steps). No LDS aliasing anywhere.
__global__ __launch_bounds__(256) void filter_kernel(
        const unsigned short* __restrict__ convout, const float* __restrict__ upf,
        const float* __restrict__ dnf, float* __restrict__ out) {
    __shared__ __align__(16) float lds0[18200];
    __shared__ float uf[12], df[12];
    float* bufA = lds0;
    float* C    = lds0 + 9240;
    int tid = threadIdx.x;
    int p = blockIdx.x;
    const unsigned short* src = convout + (size_t)p * (HO * CSTRIDE);
    float* dst = out + (size_t)p * (64 * 64);
    // phase 0: filter taps + pad zeroing (no shared reads yet)
    if (tid < 12) { uf[tid] = upf[tid] * 2.f; df[tid] = dnf[tid]; }
    for (int idx = tid; idx < 1056; idx += 256) {
        int r = idx / 132, cc = idx - r * 132;
        bufA[(r < 4 ? r : 62 + r) * 132 + cc] = 0.f;
    }
    for (int idx = tid; idx < 640; idx += 256) {
        int r = idx / 10, q = idx - r * 10;
        C[r * 140 + (q < 5 ? q : 128 + q)] = 0.f;   // i = 0..4 and 133..137
    }
    __syncthreads();   // uf/df + pads visible before any read (r18 fix)
    // phase 1: up-x from global, writes bufA rows 4..65
    for (int task = tid; task < 62 * 16; task += 256) {
        int y = task >> 4, g = task & 15;
        const unsigned short* row = src + y * CSTRIDE + (g << 2);
        ushort4 c0 = (g > 0)  ? *(const ushort4*)(row - 4) : make_ushort4(0, 0, 0, 0);
        ushort4 c1 = *(const ushort4*)(row);
        ushort4 c2 = (g < 15) ? *(const ushort4*)(row + 4) : make_ushort4(0, 0, 0, 0);
        float xv[10];
        xv[0] = bf2f(c0.x); xv[1] = bf2f(c0.y); xv[2] = bf2f(c0.z); xv[3] = bf2f(c0.w);
        xv[4] = bf2f(c1.x); xv[5] = bf2f(c1.y); xv[6] = bf2f(c1.z); xv[7] = bf2f(c1.w);
        xv[8] = bf2f(c2.x); xv[9] = bf2f(c2.y);
        float* arow = bufA + (y + 4) * 132 + (g << 3);
#pragma unroll
        for (int dd = 0; dd < 4; ++dd) {
            float oe = 0.f, oo = 0.f;
#pragma unroll
            for (int v = 0; v < 6; ++v) {
                oe += uf[2 * v + 1] * xv[dd + 5 - v];
                oo += uf[2 * v] * xv[dd + 6 - v];
            }
            *(float2*)(arow + 2 * dd) = make_float2(oe, oo);
        }
    }
    __syncthreads();
    // phase 2: vertical register pipeline (no barriers inside)
    {
        const int c = tid & 127;
        const int h = tid >> 7;           // wave-uniform
        if (h == 0) vpipe<0, 35, 3>(bufA, C, c, uf, df);
        else        vpipe<29, 38, 6>(bufA, C, c, uf, df);
    }
    __syncthreads();
    // phase 3: down-x, C rows -> output
    for (int idx = tid; idx < 64 * 64; idx += 256) {
        int yo = idx >> 6, xo = idx & 63;
        const float2* a = (const float2*)&C[yo * 140 + 2 * xo];
        float v[12];
#pragma unroll
        for (int q = 0; q < 6; ++q) {
            float2 u2 = a[q];
            v[2 * q] = u2.x; v[2 * q + 1] = u2.y;
        }
        float acc2 = 0.f;
#pragma unroll
        for (int u = 0; u < 12; ++u) acc2 += df[u] * v[11 - u];
        dst[idx] = acc2;
    }
}

extern "C" void kernel_launch(void* const* d_in, const int* in_sizes, int n_in,
                              void* d_out, int out_size, void* d_ws, size_t ws_size,
                              hipStream_t stream) {
    const float* input       = (const float*)d_in[0];
    const float* style       = (const float*)d_in[1];
    const float* conv_weight = (const float*)d_in[2];
    const float* mod_w       = (const float*)d_in[3];
    const float* mod_b       = (const float*)d_in[4];
    const float* bias        = (const float*)d_in[5];
    const float* up_filter   = (const float*)d_in[6];
    const float* down_filter = (const float*)d_in[7];
    float* ws  = (float*)d_ws;
    float* out = (float*)d_out;
    float* s_buf   = ws;
    float* dm      = ws + 2048;
    float* wsq     = ws + 4096;
    unsigned short* wh      = (unsigned short*)(ws + 69632);
    float* zpage            = ws + 364544;
    unsigned short* xh      = (unsigned short*)(ws + 659456);
    unsigned short* convout = (unsigned short*)(ws + 9048064);

    hipLaunchKernelGGL(mod_kernel, dim3(512), dim3(256), 0, stream, style, mod_w, mod_b, s_buf, zpage);
    hipLaunchKernelGGL(wsplit_kernel, dim3(256), dim3(256), 0, stream, conv_weight, wsq, wh);
    hipLaunchKernelGGL(demod_kernel, dim3(512), dim3(256), 0, stream, s_buf, wsq, dm);
    hipLaunchKernelGGL(xsplit_kernel, dim3(512), dim3(256), 0, stream, input, s_buf, xh);
    hipLaunchKernelGGL(conv_mfma, dim3(32, 2, 8), dim3(256), 73728, stream,
                       xh, wh, (const unsigned short*)zpage, dm, bias, convout);
    hipLaunchKernelGGL(filter_kernel, dim3(2048), dim3(256), 0, stream,
                       convout, up_filter, down_filter, out);
}

// Round 20
// 98.860 us; speedup vs baseline: 1.3811x; 1.0604x over previous
//
#include <hip/hip_runtime.h>
#include <math.h>

#define B_   8
#define CIN  256
#define COUT 256
#define H_   64
#define W_   64
#define HO   62
#define WO   62
#define SDIM 512

// convout padded: [b][co][62][64] bf16 (cols 62,63 zeroed by conv epilogue)
#define CSTRIDE 64

typedef __attribute__((ext_vector_type(8))) short bf16x8;
typedef __attribute__((ext_vector_type(4))) float f32x4;

__device__ __forceinline__ unsigned short f2bf(float f) {
    unsigned int u = __float_as_uint(f);
    u += 0x7fffu + ((u >> 16) & 1u);
    return (unsigned short)(u >> 16);
}
__device__ __forceinline__ float bf2f(unsigned short h) {
    return __uint_as_float(((unsigned int)h) << 16);
}

// ws layout (floats):
// s:       [0, 2048)
// dm:      [2048, 4096)
// wsq:     [4096, 69632)
// wh:      [69632, 364544)     (9*256*256 ushort, hi only)
// zpage:   [364544, 365056)    (512 floats, zeroed by mod_kernel each launch)
// xh:      [659456, 4853760)   (8*64*64*256 ushort)
// convout: [9048064, 13111296) (8*256*62*64 ushort)

__global__ void mod_kernel(const float* __restrict__ style, const float* __restrict__ mod_w,
                           const float* __restrict__ mod_b, float* __restrict__ s_out,
                           float* __restrict__ zpage) {
    if (blockIdx.x == 0) {
        zpage[threadIdx.x] = 0.f;
        zpage[threadIdx.x + 256] = 0.f;
    }
    int wid = blockIdx.x * 4 + (threadIdx.x >> 6);
    int lane = threadIdx.x & 63;
    int b = wid >> 8, ci = wid & 255;
    float acc = 0.f;
    const float* st = style + b * SDIM;
    const float* mw = mod_w + ci * SDIM;
    for (int i = 0; i < SDIM; i += 64) acc += st[i + lane] * mw[i + lane];
    for (int m = 32; m >= 1; m >>= 1) acc += __shfl_xor(acc, m, 64);
    if (lane == 0) s_out[wid] = acc * 0.04419417382415922f + mod_b[ci]; // 1/sqrt(512)
}

__global__ void wsplit_kernel(const float* __restrict__ cw, float* __restrict__ wsq,
                              unsigned short* __restrict__ wh) {
    int idx = blockIdx.x * blockDim.x + threadIdx.x; // co*256+ci
    int co = idx >> 8, ci = idx & 255;
    const float* p = cw + (size_t)idx * 9;
    float ss = 0.f;
#pragma unroll
    for (int k = 0; k < 9; ++k) {
        float v = p[k];
        ss += v * v;
        wh[(k * COUT + co) * CIN + ci] = f2bf(v);
    }
    wsq[idx] = ss;
}

__global__ void demod_kernel(const float* __restrict__ s_in, const float* __restrict__ wsq,
                             float* __restrict__ dm) {
    int wid = blockIdx.x * 4 + (threadIdx.x >> 6);
    int lane = threadIdx.x & 63;
    int b = wid >> 8, co = wid & 255;
    float acc = 0.f;
    for (int i = 0; i < CIN; i += 64) {
        float sv = s_in[b * CIN + i + lane];
        acc += sv * sv * wsq[co * CIN + i + lane];
    }
    for (int m = 32; m >= 1; m >>= 1) acc += __shfl_xor(acc, m, 64);
    if (lane == 0) {
        const float scale = 0.020833333333333332f; // 1/48 = 1/sqrt(2304)
        float demod = rsqrtf(scale * scale * acc + 1e-8f);
        dm[wid] = demod * scale / (1.f + 1e-8f);
    }
}

// Transpose+scale: x[b][ci][y][x] f32 -> xh[b][y][x][ci] bf16.
__global__ __launch_bounds__(256) void xsplit_kernel(
        const float* __restrict__ x, const float* __restrict__ s_in,
        unsigned short* __restrict__ xh) {
    __shared__ float tile[128 * 65];
    __shared__ float s_loc[256];
    int b = blockIdx.x >> 6;
    int y = blockIdx.x & 63;
    int tid = threadIdx.x;
    s_loc[tid] = s_in[(b << 8) + tid];
    __syncthreads();
    for (int half = 0; half < 2; ++half) {
        int cb = half << 7;
        for (int f = tid; f < 2048; f += 256) {
            int ci = f >> 4, x4 = (f & 15) << 2;
            float4 v = *(const float4*)(x + ((((size_t)b << 8) + cb + ci) << 12) + (y << 6) + x4);
            float sv = s_loc[cb + ci];
            float* t = tile + ci * 65 + x4;
            t[0] = v.x * sv; t[1] = v.y * sv; t[2] = v.z * sv; t[3] = v.w * sv;
        }
        __syncthreads();
        for (int g = tid; g < 1024; g += 256) {
            int c = g & 15, xx = g >> 4;   // c: 8-ci chunk, xx: x position
            unsigned int hw[4];
#pragma unroll
            for (int q = 0; q < 4; ++q) {
                float v0 = tile[(c * 8 + 2 * q) * 65 + xx];
                float v1 = tile[(c * 8 + 2 * q + 1) * 65 + xx];
                hw[q] = (unsigned int)f2bf(v0) | ((unsigned int)f2bf(v1) << 16);
            }
            int o = ((((b << 6) + y) << 6) + xx) * 256 + cb + (c << 3);
            *(uint4*)(xh + o) = make_uint4(hw[0], hw[1], hw[2], hw[3]);
        }
        __syncthreads();
    }
}

// DMA staging helpers (global_load_lds, width 16): linear LDS dest, source
// carries the XOR bank-swizzle (pre-swizzled-source pattern).
__device__ __forceinline__ void stage_b(const unsigned short* wh, const int* bsrc,
                                        short* dst, int tid, int kyci) {
#pragma unroll
    for (int j = 0; j < 6; ++j)
        __builtin_amdgcn_global_load_lds(
            (const __attribute__((address_space(1))) unsigned int*)(wh + bsrc[j] + kyci),
            (__attribute__((address_space(3))) unsigned int*)(dst + ((tid + (j << 8)) << 3)),
            16, 0, 0);
}
__device__ __forceinline__ void stage_a(const unsigned short* a0, const unsigned short* a1,
                                        const unsigned short* a2, short* dst, int tid, int ci0) {
    __builtin_amdgcn_global_load_lds(
        (const __attribute__((address_space(1))) unsigned int*)(a0 + ci0),
        (__attribute__((address_space(3))) unsigned int*)(dst + (tid << 3)), 16, 0, 0);
    __builtin_amdgcn_global_load_lds(
        (const __attribute__((address_space(1))) unsigned int*)(a1 + ci0),
        (__attribute__((address_space(3))) unsigned int*)(dst + ((tid + 256) << 3)), 16, 0, 0);
    __builtin_amdgcn_global_load_lds(
        (const __attribute__((address_space(1))) unsigned int*)(a2 + ci0),
        (__attribute__((address_space(3))) unsigned int*)(dst + ((tid + 512) << 3)), 16, 0, 0);
}

// compute one ky-phase (static KY): 3 kx * 4 nt * 4 yr MFMAs (hi-only)
template<int KY>
__device__ __forceinline__ void conv_compute(const short* Ah, const short* Bb,
        f32x4 (&acc)[4][4], int lrow, int lch, int wy, int wc) {
#pragma unroll
    for (int kx = 0; kx < 3; ++kx) {
        int colL = lrow + kx;
        int asw = (lch ^ ((colL >> 1) & 3)) << 3;
        bf16x8 ahf[4];
#pragma unroll
        for (int yr = 0; yr < 4; ++yr) {
            int rr = wy * 4 + yr + KY;
            ahf[yr] = *(const bf16x8*)(Ah + (rr * 18 + colL) * 32 + asw);
        }
#pragma unroll
        for (int nt = 0; nt < 4; ++nt) {
            int col = wc * 64 + nt * 16 + lrow;
            int boff = (kx << 12) + (col << 5) + ((lch ^ ((col >> 1) & 3)) << 3);
            bf16x8 bhf = *(const bf16x8*)(Bb + boff);
#pragma unroll
            for (int yr = 0; yr < 4; ++yr)
                acc[yr][nt] = __builtin_amdgcn_mfma_f32_16x16x32_bf16(ahf[yr], bhf, acc[yr][nt], 0, 0, 0);
        }
    }
}

// Implicit-GEMM modulated conv, single-pass bf16 MFMA (ah*bh), async
// double-buffered staging via global_load_lds (no VGPR round-trip).
// LDS: A0/A1 768 slots, B0/B1 1536 slots, 16B each = 73728 B -> 2 blocks/CU.
__global__ __launch_bounds__(256) void conv_mfma(
        const unsigned short* __restrict__ xh,
        const unsigned short* __restrict__ wh,
        const unsigned short* __restrict__ zpage,
        const float* __restrict__ dm,
        const float* __restrict__ bias, unsigned short* __restrict__ convout) {
    extern __shared__ short lds[];

    int tid = threadIdx.x;
    int b = blockIdx.z;
    int co0 = blockIdx.y << 7;
    int sx = blockIdx.x & 3, sy = blockIdx.x >> 2;
    int x0 = sx << 4, y0 = sy << 3;
    int wid = tid >> 6, lane = tid & 63;
    int wy = wid >> 1, wc = wid & 1;
    int lrow = lane & 15, lch = lane >> 4;

    int bsrc[6];
#pragma unroll
    for (int j = 0; j < 6; ++j) {
        int u = tid + (j << 8);
        int chunk = u & 3;
        int co = (u >> 2) & 127;
        int kx = u >> 9;
        int cs = chunk ^ ((co >> 1) & 3);
        bsrc[j] = (kx << 16) + ((co0 + co) << 8) + (cs << 3);
    }
    const unsigned short* ap0;
    const unsigned short* ap1;
    const unsigned short* ap2;
#pragma unroll
    for (int k = 0; k < 3; ++k) {
        int u = tid + (k << 8);
        int t2 = u >> 2;
        int col = t2 % 18, row = t2 / 18;
        int yy = y0 + row, xx = x0 + col;
        bool ok = (u < 720) && (yy < 64) && (xx < 64);
        int cs = (u & 3) ^ ((col >> 1) & 3);
        const unsigned short* p = ok ? xh + ((((b << 6) + yy) << 6) + xx) * 256 + (cs << 3) : zpage;
        if (k == 0) ap0 = p; else if (k == 1) ap1 = p; else ap2 = p;
    }

    f32x4 acc[4][4];
#pragma unroll
    for (int i = 0; i < 4; ++i)
#pragma unroll
        for (int j = 0; j < 4; ++j) acc[i][j] = (f32x4){0.f, 0.f, 0.f, 0.f};

    stage_a(ap0, ap1, ap2, lds, tid, 0);
    stage_b(wh, bsrc, lds + 12288, tid, 0);
    __syncthreads();

#pragma unroll 1
    for (int ks = 0; ks < 8; ++ks) {
        int ci0 = ks << 5;
        int ci0n = (ks + 1) << 5;   // ks=7: harmless garbage prefetch, never read
        int pb = ks & 1;
        short* Acur = lds + (pb ? 6144 : 0);
        short* Anxt = lds + (pb ? 0 : 6144);
        short* Bcur = lds + (pb ? 24576 : 12288);
        short* Balt = lds + (pb ? 12288 : 24576);
        stage_b(wh, bsrc, Balt, tid, 196608 + ci0);
        conv_compute<0>(Acur, Bcur, acc, lrow, lch, wy, wc);
        __syncthreads();
        stage_b(wh, bsrc, Bcur, tid, 2 * 196608 + ci0);
        conv_compute<1>(Acur, Balt, acc, lrow, lch, wy, wc);
        __syncthreads();
        stage_b(wh, bsrc, Balt, tid, ci0n);
        stage_a(ap0, ap1, ap2, Anxt, tid, ci0n);
        conv_compute<2>(Acur, Bcur, acc, lrow, lch, wy, wc);
        __syncthreads();
    }

    // epilogue: D row = x-pos = 4*lch + j, D col = co = 16*nt + lrow.
    // Cols 62,63 (xs4==60, z/w elements) are zeroed so filter's unguarded
    // global reads see clean right-padding.
    int xs4 = x0 + (lch << 2);
#pragma unroll
    for (int nt = 0; nt < 4; ++nt) {
        int co = co0 + wc * 64 + nt * 16 + lrow;
        float dmv = dm[(b << 8) + co];
        float bv = bias[co];
#pragma unroll
        for (int yr = 0; yr < 4; ++yr) {
            int y = y0 + wy * 4 + yr;
            if (y < HO) {
                ushort4 o;
                o.x = f2bf(acc[yr][nt][0] * dmv + bv);
                o.y = f2bf(acc[yr][nt][1] * dmv + bv);
                o.z = f2bf(acc[yr][nt][2] * dmv + bv);
                o.w = f2bf(acc[yr][nt][3] * dmv + bv);
                if (xs4 == 60) { o.z = 0; o.w = 0; }
                *(ushort4*)(convout + ((size_t)((b << 8) + co) * HO + y) * CSTRIDE + xs4) = o;
            }
        }
    }
}

// Vertical pipeline: up-y + leaky + down-y for one column c, rows h-half.
// Register-resident; bufA and C are bf16 in LDS (halves LDS -> 4 blocks/CU).
// Pair n produces t rows 2n,2n+1 (rows >=128 zero); output yo emitted at
// n = yo+3 from t rows 2n-11..2n. Ring indices compile-time (rule #20).
template<int N0, int NSTEPS, int KSTART>
__device__ __forceinline__ void vpipe(const unsigned short* __restrict__ bufA,
                                      unsigned short* __restrict__ C, int c,
                                      const float* __restrict__ uf,
                                      const float* __restrict__ df) {
    const float SQ2 = 1.4142135623730951f;
    float ufr[12], dfr[12];
#pragma unroll
    for (int i = 0; i < 12; ++i) { ufr[i] = uf[i]; dfr[i] = df[i]; }
    float w[7];
#pragma unroll
    for (int d = 0; d < 7; ++d) w[d] = bf2f(bufA[(N0 + d) * 136 + c]);
    float pcur = bf2f(bufA[((N0 + 7) > 69 ? 69 : (N0 + 7)) * 136 + c]);
    float t[13];
#pragma unroll
    for (int i = 0; i < 13; ++i) t[i] = 0.f;
#pragma unroll
    for (int k = 0; k < NSTEPS; ++k) {
        const int n = N0 + k;
        const int rnext = (n + 8) > 69 ? 69 : (n + 8);
        float pnext = bf2f(bufA[rnext * 136 + c]);     // issued early, used next step
        float te = 0.f, to = 0.f;
#pragma unroll
        for (int d = 0; d < 6; ++d) te += ufr[11 - 2 * d] * w[d];
#pragma unroll
        for (int d = 1; d < 7; ++d) to += ufr[12 - 2 * d] * w[d];
        te = (te >= 0.f ? te : 0.2f * te) * SQ2;
        to = (to >= 0.f ? to : 0.2f * to) * SQ2;
        if (2 * n < 128) {
            t[(2 * n) % 13] = te;
            t[(2 * n + 1) % 13] = to;
        } else {
            t[(2 * n) % 13] = 0.f;
            t[(2 * n + 1) % 13] = 0.f;
        }
        if (k >= KSTART) {
            const int yo = n - 3;
            float acc = 0.f;
#pragma unroll
            for (int u = 0; u < 12; ++u) {
                const int r = 2 * n - u;               // = 2*yo+6-u
                const int ri = ((r % 13) + 13) % 13;   // compile-time
                acc += dfr[u] * t[ri];
            }
            C[yo * 140 + 5 + c] = f2bf(acc);
        }
#pragma unroll
        for (int d = 0; d < 6; ++d) w[d] = w[d + 1];
        w[6] = pcur;
        pcur = pnext;
    }
}

// Fused upfirdn chain per (b,c) plane. 62x62 bf16 in -> 64x64 f32 out.
// Chain reordered via commutativity: up-x -> up-y -> leaky -> DOWN-Y -> DOWN-X.
// bufA: bf16 [70][136] (stride 272 B -> 16B-aligned uint4 row stores; rows
//   4..65 data, pad rows zeroed). C: bf16 [64][140] (i = 5+c data, i 0..4 and
//   133..137 zero pads). Total LDS ~37 KB -> 4 blocks/CU (r19 was 73 KB -> 2).
// bf16 intermediates add ~2^-9 rel. error each (budget 0.096, current 0.031).
// 256 threads = 128 columns x 2 row-halves; no barriers inside vpipe.
__global__ __launch_bounds__(256) void filter_kernel(
        const unsigned short* __restrict__ convout, const float* __restrict__ upf,
        const float* __restrict__ dnf, float* __restrict__ out) {
    __shared__ __align__(16) unsigned short bufA[70 * 136];
    __shared__ __align__(16) unsigned short C[64 * 140];
    __shared__ float uf[12], df[12];
    int tid = threadIdx.x;
    int p = blockIdx.x;
    const unsigned short* src = convout + (size_t)p * (HO * CSTRIDE);
    float* dst = out + (size_t)p * (64 * 64);
    // phase 0: filter taps + pad zeroing (no shared reads yet)
    if (tid < 12) { uf[tid] = upf[tid] * 2.f; df[tid] = dnf[tid]; }
    for (int idx = tid; idx < 1088; idx += 256) {
        int r = idx >> 7, cc = idx & 127;          // 8 pad rows x 128 used cols
        bufA[(r < 4 ? r : 62 + r) * 136 + cc] = 0;
    }
    for (int idx = tid; idx < 640; idx += 256) {
        int r = idx / 10, q = idx - r * 10;
        C[r * 140 + (q < 5 ? q : 128 + q)] = 0;    // i = 0..4 and 133..137
    }
    __syncthreads();   // uf/df + pads visible before any read (r18 fix)
    // phase 1: up-x from global, writes bufA rows 4..65 (8 bf16 = one uint4)
    for (int task = tid; task < 62 * 16; task += 256) {
        int y = task >> 4, g = task & 15;
        const unsigned short* row = src + y * CSTRIDE + (g << 2);
        ushort4 c0 = (g > 0)  ? *(const ushort4*)(row - 4) : make_ushort4(0, 0, 0, 0);
        ushort4 c1 = *(const ushort4*)(row);
        ushort4 c2 = (g < 15) ? *(const ushort4*)(row + 4) : make_ushort4(0, 0, 0, 0);
        float xv[10];
        xv[0] = bf2f(c0.x); xv[1] = bf2f(c0.y); xv[2] = bf2f(c0.z); xv[3] = bf2f(c0.w);
        xv[4] = bf2f(c1.x); xv[5] = bf2f(c1.y); xv[6] = bf2f(c1.z); xv[7] = bf2f(c1.w);
        xv[8] = bf2f(c2.x); xv[9] = bf2f(c2.y);
        unsigned int hw[4];
#pragma unroll
        for (int dd = 0; dd < 4; ++dd) {
            float oe = 0.f, oo = 0.f;
#pragma unroll
            for (int v = 0; v < 6; ++v) {
                oe += uf[2 * v + 1] * xv[dd + 5 - v];
                oo += uf[2 * v] * xv[dd + 6 - v];
            }
            hw[dd] = (unsigned int)f2bf(oe) | ((unsigned int)f2bf(oo) << 16);
        }
        *(uint4*)(bufA + (y + 4) * 136 + (g << 3)) = make_uint4(hw[0], hw[1], hw[2], hw[3]);
    }
    __syncthreads();
    // phase 2: vertical register pipeline (no barriers inside)
    {
        const int c = tid & 127;
        const int h = tid >> 7;           // wave-uniform
        if (h == 0) vpipe<0, 35, 3>(bufA, C, c, uf, df);
        else        vpipe<29, 38, 6>(bufA, C, c, uf, df);
    }
    __syncthreads();
    // phase 3: down-x, C rows (bf16) -> output f32
    for (int idx = tid; idx < 64 * 64; idx += 256) {
        int yo = idx >> 6, xo = idx & 63;
        const unsigned int* cu = (const unsigned int*)(C + yo * 140) + xo;
        float v[12];
#pragma unroll
        for (int q = 0; q < 6; ++q) {
            unsigned int u2 = cu[q];
            v[2 * q] = bf2f((unsigned short)(u2 & 0xffffu));
            v[2 * q + 1] = bf2f((unsigned short)(u2 >> 16));
        }
        float acc2 = 0.f;
#pragma unroll
        for (int u = 0; u < 12; ++u) acc2 += df[u] * v[11 - u];
        dst[idx] = acc2;
    }
}

extern "C" void kernel_launch(void* const* d_in, const int* in_sizes, int n_in,
                              void* d_out, int out_size, void* d_ws, size_t ws_size,
                              hipStream_t stream) {
    const float* input       = (const float*)d_in[0];
    const float* style       = (const float*)d_in[1];
    const float* conv_weight = (const float*)d_in[2];
    const float* mod_w       = (const float*)d_in[3];
    const float* mod_b       = (const float*)d_in[4];
    const float* bias        = (const float*)d_in[5];
    const float* up_filter   = (const float*)d_in[6];
    const float* down_filter = (const float*)d_in[7];
    float* ws  = (float*)d_ws;
    float* out = (float*)d_out;
    float* s_buf   = ws;
    float* dm      = ws + 2048;
    float* wsq     = ws + 4096;
    unsigned short* wh      = (unsigned short*)(ws + 69632);
    float* zpage            = ws + 364544;
    unsigned short* xh      = (unsigned short*)(ws + 659456);
    unsigned short* convout = (unsigned short*)(ws + 9048064);

    hipLaunchKernelGGL(mod_kernel, dim3(512), dim3(256), 0, stream, style, mod_w, mod_b, s_buf, zpage);
    hipLaunchKernelGGL(wsplit_kernel, dim3(256), dim3(256), 0, stream, conv_weight, wsq, wh);
    hipLaunchKernelGGL(demod_kernel, dim3(512), dim3(256), 0, stream, s_buf, wsq, dm);
    hipLaunchKernelGGL(xsplit_kernel, dim3(512), dim3(256), 0, stream, input, s_buf, xh);
    hipLaunchKernelGGL(conv_mfma, dim3(32, 2, 8), dim3(256), 73728, stream,
                       xh, wh, (const unsigned short*)zpage, dm, bias, convout);
    hipLaunchKernelGGL(filter_kernel, dim3(2048), dim3(256), 0, stream,
                       convout, up_filter, down_filter, out);
}